// Round 14
// baseline (50.087 us; speedup 1.0000x reference)
//
#include <hip/hip_runtime.h>
#include <math.h>

#define BATCH 64
#define TT 24
#define HW 65536
#define PIX 50
#define NN 24
#define GAMMA_F 0.001f
#define INVG 1000.0f
#define BIGF 100000000.0f
#define PARTS 4        // blocks per batch in local top-k
#define PSIZE (HW / PARTS)   // 16384 elements per part
#define CAPL 512       // candidate cap per part
#define NBLK 1600      // dtw blocks (2 problems each)
#define NCAND (PARTS * PIX)  // 200 candidates per batch

__device__ __forceinline__ unsigned ordered_key(float f) {
    unsigned u = __float_as_uint(f);
    return (u & 0x80000000u) ? ~u : (u | 0x80000000u);
}

// expand 16x4-bit nibble counts (a4) into 4x u64 of 16x16-bit fields (a16).
__device__ __forceinline__ void expand_add(unsigned long long a4,
                                           unsigned long long* a16) {
    #pragma unroll
    for (int f = 0; f < 4; ++f) {
        unsigned long long x = (a4 >> (16 * f)) & 0xFFFFull;
        a16[f] += (x & 0xFull) | ((x & 0xF0ull) << 12)
                | ((x & 0xF00ull) << 24) | ((x & 0xF000ull) << 36);
    }
}

// ---------------- Kernel 1: per-quarter exact local top-50 ---------------
// Atomic-free 4-bit MSB radix descent on key>>16. ONE barrier per level:
// parity-double-buffered wred + all-thread broadcast sum replaces the
// tid<4 partial + second barrier. Then collect (key>>16 >= t*) and rank
// exactly under (value desc, index asc) — exact lax.top_k tie semantics.
__global__ __launch_bounds__(1024) void topk_local_kernel(
        const float* __restrict__ mask, unsigned long long* __restrict__ cands) {
    __shared__ unsigned keys[PSIZE];            // 64 KB
    __shared__ unsigned long long wred[2][16][4];
    __shared__ unsigned ck[CAPL];
    __shared__ unsigned ci[CAPL];
    __shared__ unsigned ncand;

    const int tid  = threadIdx.x;
    const int w    = tid >> 6;
    const int lane = tid & 63;
    const int b    = blockIdx.x >> 2;
    const int part = blockIdx.x & 3;
    if (tid == 0) ncand = 0;

    unsigned long long a16[4] = {0, 0, 0, 0};

    // ---- HBM staging pass: write keys to LDS + count level-3 digits ----
    const float4* m4 = (const float4*)(mask + (size_t)b * HW + part * PSIZE);
    {
        unsigned long long a4 = 0;
        #pragma unroll
        for (int i = 0; i < 4; ++i) {
            int c = tid + 1024 * i;
            float4 v = m4[c];
            uint4 k;
            k.x = ordered_key(v.x); k.y = ordered_key(v.y);
            k.z = ordered_key(v.z); k.w = ordered_key(v.w);
            ((uint4*)keys)[c] = k;              // ds_write_b128, coalesced
            a4 += 1ull << (4 * (k.x >> 28));
            a4 += 1ull << (4 * (k.y >> 28));
            a4 += 1ull << (4 * (k.z >> 28));
            a4 += 1ull << (4 * (k.w >> 28));
            if (i & 1) { expand_add(a4, a16); a4 = 0; }
        }
    }

    // ---- 4-level descent; level 3's counts already in a16 ----
    unsigned pref = 0, himask = 0, remaining = PIX;
    #pragma unroll
    for (int d = 3; d >= 0; --d) {
        const int sh = 4 * d;
        if (d < 3) {
            a16[0] = a16[1] = a16[2] = a16[3] = 0;
            unsigned long long a4 = 0;
            #pragma unroll
            for (int i = 0; i < 4; ++i) {
                uint4 k = ((const uint4*)keys)[tid + 1024 * i];   // ds_read_b128
                unsigned k16;
                k16 = k.x >> 16; if ((k16 & himask) == pref) a4 += 1ull << (4 * ((k16 >> sh) & 0xFu));
                k16 = k.y >> 16; if ((k16 & himask) == pref) a4 += 1ull << (4 * ((k16 >> sh) & 0xFu));
                k16 = k.z >> 16; if ((k16 & himask) == pref) a4 += 1ull << (4 * ((k16 >> sh) & 0xFu));
                k16 = k.w >> 16; if ((k16 & himask) == pref) a4 += 1ull << (4 * ((k16 >> sh) & 0xFu));
                if (i & 1) { expand_add(a4, a16); a4 = 0; }
            }
        }
        // wave butterfly on the 4 packed accumulators
        #pragma unroll
        for (int off = 32; off > 0; off >>= 1) {
            a16[0] += __shfl_down(a16[0], off);
            a16[1] += __shfl_down(a16[1], off);
            a16[2] += __shfl_down(a16[2], off);
            a16[3] += __shfl_down(a16[3], off);
        }
        if (lane == 0) {
            wred[d & 1][w][0] = a16[0]; wred[d & 1][w][1] = a16[1];
            wred[d & 1][w][2] = a16[2]; wred[d & 1][w][3] = a16[3];
        }
        __syncthreads();   // single barrier per level (parity buffer protects
                           // the next write to this buffer, two levels away)
        unsigned long long cc[4] = {0, 0, 0, 0};
        #pragma unroll
        for (int i = 0; i < 16; ++i) {          // same addr across lanes ->
            cc[0] += wred[d & 1][i][0];         // LDS broadcast, conflict-free
            cc[1] += wred[d & 1][i][1];
            cc[2] += wred[d & 1][i][2];
            cc[3] += wred[d & 1][i][3];
        }
        unsigned S = 0, sel = 0;
        #pragma unroll
        for (int q = 15; q >= 0; --q) {
            unsigned c = (unsigned)((cc[q >> 2] >> (16 * (q & 3))) & 0xFFFFull);
            if (S + c >= remaining) { sel = (unsigned)q; break; }
            S += c;
        }
        remaining -= S;
        pref   |= sel << sh;
        himask |= 0xFu << sh;
    }
    const unsigned thresh = pref;      // 50th-largest key>>16

    // ---- collect candidates from LDS; indices are within-batch ----
    for (int c = tid; c < PSIZE / 4; c += 1024) {
        uint4 k = ((const uint4*)keys)[c];
        unsigned kk[4] = {k.x, k.y, k.z, k.w};
        #pragma unroll
        for (int e = 0; e < 4; ++e) {
            if ((kk[e] >> 16) >= thresh) {
                unsigned pos = atomicAdd(&ncand, 1u);
                if (pos < CAPL) { ck[pos] = kk[e]; ci[pos] = (unsigned)(part * PSIZE + 4 * c + e); }
            }
        }
    }
    __syncthreads();

    // ---- exact local ranking; write local top-50 packed (key,~idx) ----
    const int nc = (int)min(ncand, (unsigned)CAPL);
    for (int c = tid; c < nc; c += 1024) {
        unsigned long long me =
            ((unsigned long long)ck[c] << 32) | (unsigned long long)(~ci[c]);
        int rank = 0;
        for (int j = 0; j < nc; ++j) {
            unsigned long long o =
                ((unsigned long long)ck[j] << 32) | (unsigned long long)(~ci[j]);
            rank += (o > me);
        }
        if (rank < PIX) cands[(size_t)blockIdx.x * PIX + rank] = me;
    }
}

// ---------------- Kernel 2: per-batch merge 200 -> exact top-50 ----------
__global__ __launch_bounds__(256) void merge_kernel(
        const unsigned long long* __restrict__ cands, int* __restrict__ topIdx) {
    __shared__ unsigned long long cl[NCAND];
    const int b   = blockIdx.x;
    const int tid = threadIdx.x;
    for (int i = tid; i < NCAND; i += 256) cl[i] = cands[(size_t)b * NCAND + i];
    __syncthreads();
    if (tid < NCAND) {
        unsigned long long me = cl[tid];
        int rank = 0;
        for (int j = 0; j < NCAND; ++j) rank += (cl[j] > me);
        if (rank < PIX) topIdx[b * PIX + rank] = (int)(~(unsigned)(me & 0xFFFFFFFFull));
    }
}

// ---------------- Kernel 3: soft-DTW fwd+bwd (register wavefront) --------
// One wave per block, 2 problems (lanes 0-23 / 32-55). Backward uses a
// -INF-padded R tile: boundary weights become exp(-INF)=0 with NO selects.
__global__ __launch_bounds__(64, 2) void dtw_kernel(
        const float* __restrict__ pred, const float* __restrict__ truth,
        const int* __restrict__ topIdx, float2* __restrict__ parts) {
    __shared__ float Rr[65][27];     // +pad row 64; stride 27 -> conflict-free
    __shared__ float P[64];

    const int lane = threadIdx.x;
    const int half = lane >> 5;
    const int r    = lane & 31;
    const bool rowAct = (r < NN);
    const int hb   = half << 5;

    const int np  = 2 * blockIdx.x + half;    // global problem 0..3199
    const int b   = np / PIX;                 // same batch for both halves
    const int npb = np - b * PIX;             // within-batch problem 0..49

    float tv = 0.0f, pv = 0.0f;
    if (rowAct) {
        int f  = npb * NN + r;                // within-batch flat (t,p) index
        int t  = f / PIX;
        int pp = f - t * PIX;
        size_t a = (size_t)(b * TT + t) * HW + (size_t)topIdx[b * PIX + pp];
        tv = truth[a];
        pv = pred[a];
    }
    P[lane] = pv;

    // ---- -INF padding for the backward reads ----
    if (rowAct) Rr[lane][NN] = -INFINITY;               // own col-24 pad
    if (lane < NN + 1) Rr[NN][lane] = -INFINITY;        // row 24, cols 0..24
    if (lane >= 32 && lane < 32 + NN + 1) Rr[32 + NN][lane - 32] = -INFINITY;

    // ---- forward: lane r holds row i=r+1; step s computes R[i][s-i] ----
    float Rprev = BIGF, Rprev2 = BIGF;        // R[i][j-1], R[i][j-2]
    #pragma unroll
    for (int s = 2; s <= 2 * NN; ++s) {
        int j = s - 1 - r;
        bool act = rowAct && (j >= 1) && (j <= NN);
        float up   = __shfl_up(Rprev, 1);     // R[i-1][j]
        float diag = __shfl_up(Rprev2, 1);    // R[i-1][j-1]
        int jc = min(max(j - 1, 0), NN - 1);  // med3 clamp
        float pj = P[hb + jc];
        if (r == 0) { up = BIGF; diag = (s == 2) ? 0.0f : BIGF; }
        float mn = fminf(diag, fminf(up, Rprev));
        float z = __expf((mn - diag) * INVG) + __expf((mn - up) * INVG)
                + __expf((mn - Rprev) * INVG);
        float d = tv - pj;
        float Rnew = d * d + mn - GAMMA_F * __logf(z);
        if (act) {
            Rr[lane][j - 1] = Rnew;           // stage for backward
            Rprev2 = Rprev;
            Rprev  = Rnew;
        }
    }
    float accS = 0.0f, accT = 0.0f;
    if (r == NN - 1) accS = Rprev;            // R[24][24] (loss_shape)

    // ---- backward: unconditional padded reads ----
    float Eprev = 0.0f, Eprev2 = 0.0f;        // own E[i][j+1], E[i][j+2]
    if (r == NN - 1) Eprev = 1.0f;            // E[24][24]=1 (Omega term = 0)
    float tnext = __shfl_down(tv, 1);         // t[i] (row i+1's value)
    #pragma unroll
    for (int s = 2 * NN - 1; s >= 2; --s) {
        int j = s - 1 - r;
        bool act = rowAct && (j >= 1) && (j <= NN);
        float eUp   = __shfl_down(Eprev, 1);  // E[i+1][j]
        float eDiag = __shfl_down(Eprev2, 1); // E[i+1][j+1]
        int jm1 = min(max(j - 1, 0), NN);
        int jp  = min(max(j,     0), NN);
        float rij    = Rr[lane][jm1];
        float rRight = Rr[lane][jp];          // j==24 -> col pad -INF
        float rDown  = Rr[lane + 1][jm1];     // r==23 -> row pad -INF
        float rDiag  = Rr[lane + 1][jp];
        float pjm1 = P[hb + jm1];
        float pj   = P[hb + jp];
        float da = tnext - pjm1; da *= da;    // D[i+1][j]
        float db = tv - pj;      db *= db;    // D[i][j+1]
        float dc = tnext - pj;   dc *= dc;    // D[i+1][j+1]
        float aw = __expf((rDown  - rij - da) * INVG);
        float bw = __expf((rRight - rij - db) * INVG);
        float cw = __expf((rDiag  - rij - dc) * INVG);
        float Enew = aw * eUp + bw * Eprev + cw * eDiag;
        if (act) {
            float dd = (float)(r + 1 - j);
            accT += Enew * dd * dd;           // E * Omega, own row slice
            Eprev2 = Eprev;
            Eprev  = Enew;
        }
    }

    // ---- wave butterfly (deterministic) + plain partial store ----
    #pragma unroll
    for (int off = 32; off > 0; off >>= 1) {
        accS += __shfl_xor(accS, off);
        accT += __shfl_xor(accT, off);
    }
    if (lane == 0) parts[blockIdx.x] = make_float2(accS, accT);
}

// ---------------- Kernel 4: deterministic final reduction ----------------
__global__ void finalize_kernel(const float2* __restrict__ parts,
                                float* __restrict__ out) {
    __shared__ double sd[256];
    __shared__ double td[256];
    int tid = threadIdx.x;
    double s = 0.0, t = 0.0;
    const float4* p4 = (const float4*)parts;          // 2 parts per load
    for (int i = tid; i < NBLK / 2; i += 256) {
        float4 v = p4[i];
        s += (double)v.x + (double)v.z;
        t += (double)v.y + (double)v.w;
    }
    sd[tid] = s; td[tid] = t;
    __syncthreads();
    for (int off = 128; off > 0; off >>= 1) {
        if (tid < off) { sd[tid] += sd[tid + off]; td[tid] += td[tid + off]; }
        __syncthreads();
    }
    if (tid == 0) {
        double loss_shape    = sd[0] / (double)(BATCH * PIX);
        double loss_temporal = td[0] / ((double)(BATCH * PIX) * (double)(NN * NN));
        out[0] = (float)(0.1 * loss_shape + 0.9 * loss_temporal);
    }
}

extern "C" void kernel_launch(void* const* d_in, const int* in_sizes, int n_in,
                              void* d_out, int out_size, void* d_ws, size_t ws_size,
                              hipStream_t stream) {
    const float* pred  = (const float*)d_in[0];
    const float* truth = (const float*)d_in[1];
    const float* mask  = (const float*)d_in[2];

    char* ws = (char*)d_ws;
    unsigned long long* cands = (unsigned long long*)ws;               // 102400 B
    int*    topIdx = (int*)(ws + 102400);                              // 12800 B
    float2* parts  = (float2*)(ws + 102400 + 12800);                   // 12800 B

    topk_local_kernel<<<BATCH * PARTS, 1024, 0, stream>>>(mask, cands);
    merge_kernel<<<BATCH, 256, 0, stream>>>(cands, topIdx);
    dtw_kernel<<<NBLK, 64, 0, stream>>>(pred, truth, topIdx, parts);
    finalize_kernel<<<1, 256, 0, stream>>>(parts, (float*)d_out);
}